// Round 4
// baseline (1105.248 us; speedup 1.0000x reference)
//
#include <hip/hip_runtime.h>
#include <stdint.h>

// Problem: B=32, S=2048, E2=1024, D=512
//   c[b][d]    = b_att[d] + sum_k dec[b][k] * W_att[1024+k][d]
//   att[b][s]  = sum_d tanh( sum_e x[b][s][e]*W_att[e][d] + c[b][d] ) * v[d]
//   w          = softmax(att, axis=s)
//   out[b][e]  = sum_s w[b][s] * x[b][s][e]
//
// ws layout: [0,256K) attention f32[65536]; [256K,320K) cbias f32[16384];
//            [320K, 320K+1MiB) W_enc bf16, pre-swizzled per 32-k chunk.

typedef __attribute__((ext_vector_type(8))) __bf16 bf16x8;
typedef __attribute__((ext_vector_type(4))) float f32x4;

__device__ __forceinline__ uint16_t f32_to_bf16_rne(float f) {
  union { float f; uint32_t u; } v; v.f = f;
  uint32_t u = v.u;
  return (uint16_t)((u + 0x7FFFu + ((u >> 16) & 1u)) >> 16);
}

__device__ __forceinline__ float tanh_fast(float x) {
  float e = __expf(2.0f * x);
  return 1.0f - 2.0f * __builtin_amdgcn_rcpf(e + 1.0f);
}

// ---------------- Kernel A: prep ----------------
// 64 blocks x 256 threads. (1) zero d_out (2) cbias (3) W_enc bf16 image.
// W image (BK=32): chunk c in [0,32), row d in [0,512), 16B unit t in [0,4):
//   global byte (c*2048 + d*4 + t)*16 holds W_enc[c*32 + (t ^ ((d>>1)&3))*8 + i][d]
// so that a LINEAR gload_lds copy yields LDS rows of 64 B where a read at
// byte d*64 + ((l4*16) ^ (((d>>1)&3)<<4)) returns k-group l4 (bank-spread).
__global__ __launch_bounds__(256) void prep_kernel(
    const float* __restrict__ dec,   // (32,512)
    const float* __restrict__ Watt,  // (1536,512)
    const float* __restrict__ batt,  // (512)
    float* __restrict__ cbias,       // ws (32*512)
    uint16_t* __restrict__ Wb,       // ws (1024*512 bf16, image layout)
    float* __restrict__ out)         // d_out (32768) -> zero
{
  const int t = blockIdx.x * 256 + threadIdx.x;  // [0,16384)

  for (int i = t; i < 32768; i += 16384) out[i] = 0.0f;

  // cbias: one output per thread. b = t>>9, d = t&511.
  {
    const int b = t >> 9, d = t & 511;
    const float* wd = Watt + 1024 * 512 + d;
    const float* dv = dec + b * 512;
    float s0 = 0.f, s1 = 0.f, s2 = 0.f, s3 = 0.f;
    #pragma unroll 4
    for (int k = 0; k < 512; k += 4) {
      s0 += dv[k + 0] * wd[(k + 0) * 512];
      s1 += dv[k + 1] * wd[(k + 1) * 512];
      s2 += dv[k + 2] * wd[(k + 2) * 512];
      s3 += dv[k + 3] * wd[(k + 3) * 512];
    }
    cbias[t] = batt[d] + ((s0 + s1) + (s2 + s3));
  }

  // W image: 65536 16-byte units, 4 per thread.
  uint4* WbV = (uint4*)Wb;
  #pragma unroll
  for (int i = 0; i < 4; ++i) {
    const int u = t + 16384 * i;      // [0,65536)
    const int c  = u >> 11;           // chunk
    const int w  = u & 2047;
    const int d  = w >> 2;
    const int tt = w & 3;
    const int kb = c * 32 + ((tt ^ ((d >> 1) & 3)) << 3);
    uint32_t h[8];
    #pragma unroll
    for (int kk = 0; kk < 8; ++kk) {
      float f = Watt[(size_t)(kb + kk) * 512 + d];
      h[kk] = f32_to_bf16_rne(f);
    }
    uint4 val;
    val.x = h[0] | (h[1] << 16);
    val.y = h[2] | (h[3] << 16);
    val.z = h[4] | (h[5] << 16);
    val.w = h[6] | (h[7] << 16);
    WbV[u] = val;
  }
}

// ---------------- Kernel B: fused energy GEMM + tanh + dot(v), v4 ----------------
// 512 blocks x 1024 threads (16 waves, 2x8). BM=128, BN=512 (full), BK=32.
// LDS: A dbuf 2x8KB + B dbuf 2x32KB = 80 KB -> 2 blocks/CU, 32 waves/CU.
// Wave tile 64x64 (acc 4x4 f32x4 = 64 AGPR) -> ~134 unified regs, 8 waves/SIMD.
// Schedule per chunk (1 barrier): write A(c); issue av(c+1); vmcnt(1) [drain
// B(c)'s 2 gload_lds, keep av(c+1) in flight]; lgkmcnt(0); s_barrier; issue
// B(c+1); compute(c). Cross-block overlap (2 independent blocks/CU) hides
// the per-chunk stalls that 2-waves/SIMD lockstep could not.
__global__ __launch_bounds__(1024, 8) void energy_kernel(
    const float* __restrict__ x,       // (65536,1024)
    const uint16_t* __restrict__ Wb,   // W image (1 MiB)
    const float* __restrict__ cbias,   // (32,512)
    const float* __restrict__ vvec,    // (512)
    float* __restrict__ att)           // (65536), fully overwritten
{
  __shared__ __align__(16) uint8_t AL[2][128 * 64];    // 2 x 8 KB
  __shared__ __align__(16) uint8_t BL[2][512 * 64];    // 2 x 32 KB

  const int tid  = threadIdx.x;
  const int lane = tid & 63;
  const int wave = tid >> 6;
  const int wm   = wave >> 3;          // 0..1  (64-row group)
  const int wn   = wave & 7;           // 0..7  (64-col group)
  const int l15  = lane & 15;
  const int l4   = lane >> 4;
  const int brow0 = blockIdx.x * 128;
  const int b     = brow0 >> 11;

  // A staging: 1 unit/thread: r = tid>>3 in [0,128), q = tid&7 (float4 idx)
  const int r_st = tid >> 3, q_st = tid & 7;
  const int aoff = r_st * 64 + ((q_st * 8) ^ (((r_st >> 1) & 3) << 4));
  const float* asrc = x + (size_t)(brow0 + r_st) * 1024 + q_st * 4;
  const uint8_t* wbase = (const uint8_t*)Wb + (lane << 4);

  f32x4 acc[4][4];
  #pragma unroll
  for (int mf = 0; mf < 4; ++mf)
    #pragma unroll
    for (int nf = 0; nf < 4; ++nf)
      acc[mf][nf] = (f32x4){0.f, 0.f, 0.f, 0.f};

  // prologue: av(0) first (older than B(0) in the vmcnt FIFO), then B(0)
  float4 av = *(const float4*)(asrc);
  #pragma unroll
  for (int i = 0; i < 2; ++i) {
    const int u = i * 16 + wave;       // [0,32) KB units
    __builtin_amdgcn_global_load_lds(
        (const __attribute__((address_space(1))) uint32_t*)(wbase + u * 1024),
        (__attribute__((address_space(3))) uint32_t*)(&BL[0][u * 1024]),
        16, 0, 0);
  }

  #pragma unroll 2
  for (int c = 0; c < 32; ++c) {
    uint8_t* Ab = AL[c & 1];
    uint8_t* Bb = BL[c & 1];

    // write A(c) (compiler emits counted vmcnt for av only; B(c) stays)
    {
      uint32_t lo = (uint32_t)f32_to_bf16_rne(av.x) | ((uint32_t)f32_to_bf16_rne(av.y) << 16);
      uint32_t hi = (uint32_t)f32_to_bf16_rne(av.z) | ((uint32_t)f32_to_bf16_rne(av.w) << 16);
      *(uint2*)(Ab + aoff) = make_uint2(lo, hi);
    }

    if (c < 31) {
      av = *(const float4*)(asrc + (c + 1) * 32);       // issue av(c+1)
      asm volatile("s_waitcnt vmcnt(1)" ::: "memory");  // drain B(c) only
    } else {
      asm volatile("s_waitcnt vmcnt(0)" ::: "memory");
    }
    asm volatile("s_waitcnt lgkmcnt(0)" ::: "memory");
    __builtin_amdgcn_s_barrier();
    asm volatile("" ::: "memory");

    if (c < 31) {  // issue B(c+1) post-barrier; lands during compute(c)
      const uint8_t* wc = wbase + ((size_t)(c + 1) << 15);
      uint8_t* Bn = BL[(c + 1) & 1];
      #pragma unroll
      for (int i = 0; i < 2; ++i) {
        const int u = i * 16 + wave;
        __builtin_amdgcn_global_load_lds(
            (const __attribute__((address_space(1))) uint32_t*)(wc + u * 1024),
            (__attribute__((address_space(3))) uint32_t*)(Bn + u * 1024),
            16, 0, 0);
      }
    }

    // compute chunk c: 8 ds_read_b128 + 16 MFMA per wave
    bf16x8 af[4], bfr[4];
    #pragma unroll
    for (int mf = 0; mf < 4; ++mf) {
      const int r = wm * 64 + mf * 16 + l15;
      af[mf] = *(const bf16x8*)(Ab + r * 64 + ((l4 * 16) ^ (((r >> 1) & 3) << 4)));
    }
    #pragma unroll
    for (int nf = 0; nf < 4; ++nf) {
      const int d = wn * 64 + nf * 16 + l15;
      bfr[nf] = *(const bf16x8*)(Bb + d * 64 + ((l4 * 16) ^ (((d >> 1) & 3) << 4)));
    }
    #pragma unroll
    for (int mf = 0; mf < 4; ++mf)
      #pragma unroll
      for (int nf = 0; nf < 4; ++nf)
        acc[mf][nf] = __builtin_amdgcn_mfma_f32_16x16x32_bf16(af[mf], bfr[nf], acc[mf][nf], 0, 0, 0);
  }

  // ---- epilogue: tanh + dot(v); LDS-atomic reduce across the 8 wn-waves ----
  float cb[4], vv[4];
  #pragma unroll
  for (int nf = 0; nf < 4; ++nf) {
    const int d = wn * 64 + nf * 16 + l15;
    cb[nf] = cbias[b * 512 + d];
    vv[nf] = vvec[d];
  }

  __syncthreads();                       // all waves done reading AL
  float* red = (float*)AL;               // reuse 512 B of A space
  if (tid < 128) red[tid] = 0.0f;
  __syncthreads();

  #pragma unroll
  for (int mf = 0; mf < 4; ++mf) {
    float s[4] = {0.f, 0.f, 0.f, 0.f};
    #pragma unroll
    for (int nf = 0; nf < 4; ++nf) {
      #pragma unroll
      for (int j = 0; j < 4; ++j) {
        const float e = acc[mf][nf][j] + cb[nf];
        s[j] += tanh_fast(e) * vv[nf];
      }
    }
    #pragma unroll
    for (int j = 0; j < 4; ++j) {
      float r = s[j];
      r += __shfl_xor(r, 1);
      r += __shfl_xor(r, 2);
      r += __shfl_xor(r, 4);
      r += __shfl_xor(r, 8);
      if (l15 == 0) atomicAdd(&red[wm * 64 + mf * 16 + 4 * l4 + j], r);
    }
  }
  __syncthreads();
  if (tid < 128) att[brow0 + tid] = red[tid];
}

// ---------------- Kernel C: softmax over S (in place) ----------------
__global__ __launch_bounds__(256) void softmax_kernel(float* __restrict__ att) {
  const int b = blockIdx.x;
  float* row = att + b * 2048;
  const int tid = threadIdx.x;
  __shared__ float redm[4], reds[4];

  float vals[8];
  float m = -1e30f;
  #pragma unroll
  for (int i = 0; i < 8; ++i) { vals[i] = row[tid + 256 * i]; m = fmaxf(m, vals[i]); }
  #pragma unroll
  for (int msk = 1; msk < 64; msk <<= 1) m = fmaxf(m, __shfl_xor(m, msk));
  if ((tid & 63) == 0) redm[tid >> 6] = m;
  __syncthreads();
  m = fmaxf(fmaxf(redm[0], redm[1]), fmaxf(redm[2], redm[3]));

  float s = 0.f;
  #pragma unroll
  for (int i = 0; i < 8; ++i) { vals[i] = __expf(vals[i] - m); s += vals[i]; }
  #pragma unroll
  for (int msk = 1; msk < 64; msk <<= 1) s += __shfl_xor(s, msk);
  if ((tid & 63) == 0) reds[tid >> 6] = s;
  __syncthreads();
  const float inv = 1.0f / (((reds[0] + reds[1]) + (reds[2] + reds[3])));
  #pragma unroll
  for (int i = 0; i < 8; ++i) row[tid + 256 * i] = vals[i] * inv;
}

// ---------------- Kernel D: context = w @ x ----------------
__global__ __launch_bounds__(256) void context_kernel(
    const float* __restrict__ x,   // (65536,1024)
    const float* __restrict__ w,   // (32,2048)
    float* __restrict__ out)       // (32,1024), pre-zeroed
{
  const int blk = blockIdx.x;
  const int b = blk >> 4, sc = blk & 15;
  const int tid = threadIdx.x;
  const float* xb = x + ((size_t)(b * 2048 + sc * 128)) * 1024 + tid * 4;
  const float* wb = w + b * 2048 + sc * 128;

  float4 acc = {0.f, 0.f, 0.f, 0.f};
  for (int si = 0; si < 128; ++si) {
    const float ww = wb[si];
    const float4 xv = *(const float4*)(xb + (size_t)si * 1024);
    acc.x += ww * xv.x;
    acc.y += ww * xv.y;
    acc.z += ww * xv.z;
    acc.w += ww * xv.w;
  }
  float* o = out + b * 1024 + tid * 4;
  atomicAdd(o + 0, acc.x);
  atomicAdd(o + 1, acc.y);
  atomicAdd(o + 2, acc.z);
  atomicAdd(o + 3, acc.w);
}

extern "C" void kernel_launch(void* const* d_in, const int* in_sizes, int n_in,
                              void* d_out, int out_size, void* d_ws, size_t ws_size,
                              hipStream_t stream) {
  const float* x    = (const float*)d_in[0];  // (32,2048,1024)
  const float* dec  = (const float*)d_in[1];  // (32,512)
  const float* Watt = (const float*)d_in[2];  // (1536,512)
  const float* batt = (const float*)d_in[3];  // (512)
  const float* v    = (const float*)d_in[4];  // (512)
  float* out = (float*)d_out;

  uint8_t* ws = (uint8_t*)d_ws;
  float*    att   = (float*)ws;                        // 256 KB
  float*    cbias = (float*)(ws + 256 * 1024);         // 64 KB
  uint16_t* Wb    = (uint16_t*)(ws + 320 * 1024);      // 1 MiB

  prep_kernel<<<64, 256, 0, stream>>>(dec, Watt, batt, cbias, Wb, out);
  energy_kernel<<<512, 1024, 0, stream>>>(x, Wb, cbias, v, att);
  softmax_kernel<<<32, 256, 0, stream>>>(att);
  context_kernel<<<512, 256, 0, stream>>>(x, att, out);
}

// Round 5
// 157.456 us; speedup vs baseline: 7.0194x; 7.0194x over previous
//
#include <hip/hip_runtime.h>
#include <stdint.h>

// Problem: B=32, S=2048, E2=1024, D=512
//   c[b][d]    = b_att[d] + sum_k dec[b][k] * W_att[1024+k][d]
//   att[b][s]  = sum_d tanh( sum_e x[b][s][e]*W_att[e][d] + c[b][d] ) * v[d]
//   w          = softmax(att, axis=s)
//   out[b][e]  = sum_s w[b][s] * x[b][s][e]
//
// ws layout: [0,256K) attention f32[65536]; [256K,320K) cbias f32[16384];
//            [320K, 320K+1MiB) W_enc bf16, pre-swizzled per 32-k chunk.

typedef __attribute__((ext_vector_type(8))) __bf16 bf16x8;
typedef __attribute__((ext_vector_type(4))) float f32x4;

__device__ __forceinline__ uint16_t f32_to_bf16_rne(float f) {
  union { float f; uint32_t u; } v; v.f = f;
  uint32_t u = v.u;
  return (uint16_t)((u + 0x7FFFu + ((u >> 16) & 1u)) >> 16);
}

__device__ __forceinline__ float tanh_fast(float x) {
  float e = __expf(2.0f * x);
  return 1.0f - 2.0f * __builtin_amdgcn_rcpf(e + 1.0f);
}

// ---------------- Kernel A: prep (unchanged from round 4) ----------------
__global__ __launch_bounds__(256) void prep_kernel(
    const float* __restrict__ dec,   // (32,512)
    const float* __restrict__ Watt,  // (1536,512)
    const float* __restrict__ batt,  // (512)
    float* __restrict__ cbias,       // ws (32*512)
    uint16_t* __restrict__ Wb,       // ws (1024*512 bf16, image layout)
    float* __restrict__ out)         // d_out (32768) -> zero
{
  const int t = blockIdx.x * 256 + threadIdx.x;  // [0,16384)

  for (int i = t; i < 32768; i += 16384) out[i] = 0.0f;

  // cbias: one output per thread. b = t>>9, d = t&511.
  {
    const int b = t >> 9, d = t & 511;
    const float* wd = Watt + 1024 * 512 + d;
    const float* dv = dec + b * 512;
    float s0 = 0.f, s1 = 0.f, s2 = 0.f, s3 = 0.f;
    #pragma unroll 4
    for (int k = 0; k < 512; k += 4) {
      s0 += dv[k + 0] * wd[(k + 0) * 512];
      s1 += dv[k + 1] * wd[(k + 1) * 512];
      s2 += dv[k + 2] * wd[(k + 2) * 512];
      s3 += dv[k + 3] * wd[(k + 3) * 512];
    }
    cbias[t] = batt[d] + ((s0 + s1) + (s2 + s3));
  }

  // W image (BK=32): chunk c, row d, 16B unit t in [0,4):
  //   unit (c*2048 + d*4 + t) holds W_enc[c*32 + (t ^ ((d>>1)&3))*8 + i][d]
  // so a LINEAR gload_lds copy yields LDS where a read at byte
  //   d*64 + ((l4*16) ^ (((d>>1)&3)<<4))  returns k-group l4 (bank-spread).
  uint4* WbV = (uint4*)Wb;
  #pragma unroll
  for (int i = 0; i < 4; ++i) {
    const int u = t + 16384 * i;      // [0,65536)
    const int c  = u >> 11;           // chunk
    const int w  = u & 2047;
    const int d  = w >> 2;
    const int tt = w & 3;
    const int kb = c * 32 + ((tt ^ ((d >> 1) & 3)) << 3);
    uint32_t h[8];
    #pragma unroll
    for (int kk = 0; kk < 8; ++kk) {
      float f = Watt[(size_t)(kb + kk) * 512 + d];
      h[kk] = f32_to_bf16_rne(f);
    }
    uint4 val;
    val.x = h[0] | (h[1] << 16);
    val.y = h[2] | (h[3] << 16);
    val.z = h[4] | (h[5] << 16);
    val.w = h[6] | (h[7] << 16);
    WbV[u] = val;
  }
}

// ---------------- Kernel B: fused energy GEMM + tanh + dot(v), v5 ----------------
// v5 = v4 with __launch_bounds__(1024, 4): 4 waves/SIMD => 128-reg cap that
// FITS (acc 64 + operands ~50), instead of v4's 8 => 64-reg cap => total spill.
// 512 blocks x 1024 threads (16 waves, 2x8). BM=128, BN=512, BK=32.
// LDS: A dbuf 2x8KB + B dbuf 2x32KB = 80 KB. 16 waves/CU.
__global__ __launch_bounds__(1024, 4) void energy_kernel(
    const float* __restrict__ x,       // (65536,1024)
    const uint16_t* __restrict__ Wb,   // W image (1 MiB)
    const float* __restrict__ cbias,   // (32,512)
    const float* __restrict__ vvec,    // (512)
    float* __restrict__ att)           // (65536), fully overwritten
{
  __shared__ __align__(16) uint8_t AL[2][128 * 64];    // 2 x 8 KB
  __shared__ __align__(16) uint8_t BL[2][512 * 64];    // 2 x 32 KB

  const int tid  = threadIdx.x;
  const int lane = tid & 63;
  const int wave = tid >> 6;
  const int wm   = wave >> 3;          // 0..1  (64-row group)
  const int wn   = wave & 7;           // 0..7  (64-col group)
  const int l15  = lane & 15;
  const int l4   = lane >> 4;
  const int brow0 = blockIdx.x * 128;
  const int b     = brow0 >> 11;

  // A staging: 1 unit/thread: r = tid>>3 in [0,128), q = tid&7 (float4 idx)
  const int r_st = tid >> 3, q_st = tid & 7;
  const int aoff = r_st * 64 + ((q_st * 8) ^ (((r_st >> 1) & 3) << 4));
  const float* asrc = x + (size_t)(brow0 + r_st) * 1024 + q_st * 4;
  const uint8_t* wbase = (const uint8_t*)Wb + (lane << 4);

  f32x4 acc[4][4];
  #pragma unroll
  for (int mf = 0; mf < 4; ++mf)
    #pragma unroll
    for (int nf = 0; nf < 4; ++nf)
      acc[mf][nf] = (f32x4){0.f, 0.f, 0.f, 0.f};

  // prologue: av(0) first (older than B(0) in the vmcnt FIFO), then B(0)
  float4 av = *(const float4*)(asrc);
  #pragma unroll
  for (int i = 0; i < 2; ++i) {
    const int u = i * 16 + wave;       // [0,32) KB units
    __builtin_amdgcn_global_load_lds(
        (const __attribute__((address_space(1))) uint32_t*)(wbase + u * 1024),
        (__attribute__((address_space(3))) uint32_t*)(&BL[0][u * 1024]),
        16, 0, 0);
  }

  #pragma unroll 2
  for (int c = 0; c < 32; ++c) {
    uint8_t* Ab = AL[c & 1];
    uint8_t* Bb = BL[c & 1];

    // write A(c) (compiler emits counted vmcnt for av only; B(c) stays)
    {
      uint32_t lo = (uint32_t)f32_to_bf16_rne(av.x) | ((uint32_t)f32_to_bf16_rne(av.y) << 16);
      uint32_t hi = (uint32_t)f32_to_bf16_rne(av.z) | ((uint32_t)f32_to_bf16_rne(av.w) << 16);
      *(uint2*)(Ab + aoff) = make_uint2(lo, hi);
    }

    if (c < 31) {
      av = *(const float4*)(asrc + (c + 1) * 32);       // issue av(c+1)
      asm volatile("s_waitcnt vmcnt(1)" ::: "memory");  // drain B(c) only
    } else {
      asm volatile("s_waitcnt vmcnt(0)" ::: "memory");
    }
    asm volatile("s_waitcnt lgkmcnt(0)" ::: "memory");
    __builtin_amdgcn_s_barrier();
    asm volatile("" ::: "memory");

    if (c < 31) {  // issue B(c+1) post-barrier; lands during compute(c)
      const uint8_t* wc = wbase + ((size_t)(c + 1) << 15);
      uint8_t* Bn = BL[(c + 1) & 1];
      #pragma unroll
      for (int i = 0; i < 2; ++i) {
        const int u = i * 16 + wave;
        __builtin_amdgcn_global_load_lds(
            (const __attribute__((address_space(1))) uint32_t*)(wc + u * 1024),
            (__attribute__((address_space(3))) uint32_t*)(Bn + u * 1024),
            16, 0, 0);
      }
    }

    // compute chunk c: 8 ds_read_b128 + 16 MFMA per wave
    bf16x8 af[4], bfr[4];
    #pragma unroll
    for (int mf = 0; mf < 4; ++mf) {
      const int r = wm * 64 + mf * 16 + l15;
      af[mf] = *(const bf16x8*)(Ab + r * 64 + ((l4 * 16) ^ (((r >> 1) & 3) << 4)));
    }
    #pragma unroll
    for (int nf = 0; nf < 4; ++nf) {
      const int d = wn * 64 + nf * 16 + l15;
      bfr[nf] = *(const bf16x8*)(Bb + d * 64 + ((l4 * 16) ^ (((d >> 1) & 3) << 4)));
    }
    #pragma unroll
    for (int mf = 0; mf < 4; ++mf)
      #pragma unroll
      for (int nf = 0; nf < 4; ++nf)
        acc[mf][nf] = __builtin_amdgcn_mfma_f32_16x16x32_bf16(af[mf], bfr[nf], acc[mf][nf], 0, 0, 0);
  }

  // ---- epilogue: tanh + dot(v); LDS-atomic reduce across the 8 wn-waves ----
  float cb[4], vv[4];
  #pragma unroll
  for (int nf = 0; nf < 4; ++nf) {
    const int d = wn * 64 + nf * 16 + l15;
    cb[nf] = cbias[b * 512 + d];
    vv[nf] = vvec[d];
  }

  __syncthreads();                       // all waves done reading AL
  float* red = (float*)AL;               // reuse 512 B of A space
  if (tid < 128) red[tid] = 0.0f;
  __syncthreads();

  #pragma unroll
  for (int mf = 0; mf < 4; ++mf) {
    float s[4] = {0.f, 0.f, 0.f, 0.f};
    #pragma unroll
    for (int nf = 0; nf < 4; ++nf) {
      #pragma unroll
      for (int j = 0; j < 4; ++j) {
        const float e = acc[mf][nf][j] + cb[nf];
        s[j] += tanh_fast(e) * vv[nf];
      }
    }
    #pragma unroll
    for (int j = 0; j < 4; ++j) {
      float r = s[j];
      r += __shfl_xor(r, 1);
      r += __shfl_xor(r, 2);
      r += __shfl_xor(r, 4);
      r += __shfl_xor(r, 8);
      if (l15 == 0) atomicAdd(&red[wm * 64 + mf * 16 + 4 * l4 + j], r);
    }
  }
  __syncthreads();
  if (tid < 128) att[brow0 + tid] = red[tid];
}

// ---------------- Kernel C: softmax over S (in place) ----------------
__global__ __launch_bounds__(256) void softmax_kernel(float* __restrict__ att) {
  const int b = blockIdx.x;
  float* row = att + b * 2048;
  const int tid = threadIdx.x;
  __shared__ float redm[4], reds[4];

  float vals[8];
  float m = -1e30f;
  #pragma unroll
  for (int i = 0; i < 8; ++i) { vals[i] = row[tid + 256 * i]; m = fmaxf(m, vals[i]); }
  #pragma unroll
  for (int msk = 1; msk < 64; msk <<= 1) m = fmaxf(m, __shfl_xor(m, msk));
  if ((tid & 63) == 0) redm[tid >> 6] = m;
  __syncthreads();
  m = fmaxf(fmaxf(redm[0], redm[1]), fmaxf(redm[2], redm[3]));

  float s = 0.f;
  #pragma unroll
  for (int i = 0; i < 8; ++i) { vals[i] = __expf(vals[i] - m); s += vals[i]; }
  #pragma unroll
  for (int msk = 1; msk < 64; msk <<= 1) s += __shfl_xor(s, msk);
  if ((tid & 63) == 0) reds[tid >> 6] = s;
  __syncthreads();
  const float inv = 1.0f / (((reds[0] + reds[1]) + (reds[2] + reds[3])));
  #pragma unroll
  for (int i = 0; i < 8; ++i) row[tid + 256 * i] = vals[i] * inv;
}

// ---------------- Kernel D: context = w @ x ----------------
__global__ __launch_bounds__(256) void context_kernel(
    const float* __restrict__ x,   // (65536,1024)
    const float* __restrict__ w,   // (32,2048)
    float* __restrict__ out)       // (32,1024), pre-zeroed
{
  const int blk = blockIdx.x;
  const int b = blk >> 4, sc = blk & 15;
  const int tid = threadIdx.x;
  const float* xb = x + ((size_t)(b * 2048 + sc * 128)) * 1024 + tid * 4;
  const float* wb = w + b * 2048 + sc * 128;

  float4 acc = {0.f, 0.f, 0.f, 0.f};
  for (int si = 0; si < 128; ++si) {
    const float ww = wb[si];
    const float4 xv = *(const float4*)(xb + (size_t)si * 1024);
    acc.x += ww * xv.x;
    acc.y += ww * xv.y;
    acc.z += ww * xv.z;
    acc.w += ww * xv.w;
  }
  float* o = out + b * 1024 + tid * 4;
  atomicAdd(o + 0, acc.x);
  atomicAdd(o + 1, acc.y);
  atomicAdd(o + 2, acc.z);
  atomicAdd(o + 3, acc.w);
}

extern "C" void kernel_launch(void* const* d_in, const int* in_sizes, int n_in,
                              void* d_out, int out_size, void* d_ws, size_t ws_size,
                              hipStream_t stream) {
  const float* x    = (const float*)d_in[0];  // (32,2048,1024)
  const float* dec  = (const float*)d_in[1];  // (32,512)
  const float* Watt = (const float*)d_in[2];  // (1536,512)
  const float* batt = (const float*)d_in[3];  // (512)
  const float* v    = (const float*)d_in[4];  // (512)
  float* out = (float*)d_out;

  uint8_t* ws = (uint8_t*)d_ws;
  float*    att   = (float*)ws;                        // 256 KB
  float*    cbias = (float*)(ws + 256 * 1024);         // 64 KB
  uint16_t* Wb    = (uint16_t*)(ws + 320 * 1024);      // 1 MiB

  prep_kernel<<<64, 256, 0, stream>>>(dec, Watt, batt, cbias, Wb, out);
  energy_kernel<<<512, 1024, 0, stream>>>(x, Wb, cbias, v, att);
  softmax_kernel<<<32, 256, 0, stream>>>(att);
  context_kernel<<<512, 256, 0, stream>>>(x, att, out);
}

// Round 6
// 156.198 us; speedup vs baseline: 7.0760x; 1.0081x over previous
//
#include <hip/hip_runtime.h>
#include <stdint.h>

// Problem: B=32, S=2048, E2=1024, D=512
//   c[b][d]    = b_att[d] + sum_k dec[b][k] * W_att[1024+k][d]
//   att[b][s]  = sum_d tanh( sum_e x[b][s][e]*W_att[e][d] + c[b][d] ) * v[d]
//   w          = softmax(att, axis=s)
//   out[b][e]  = sum_s w[b][s] * x[b][s][e]
//
// ws layout: [0,256K) attention f32[65536]; [256K,320K) cbias f32[16384];
//            [320K, 320K+1MiB) W_enc bf16, pre-swizzled per 32-k chunk.

typedef __attribute__((ext_vector_type(8))) __bf16 bf16x8;
typedef __attribute__((ext_vector_type(4))) float f32x4;

__device__ __forceinline__ uint16_t f32_to_bf16_rne(float f) {
  union { float f; uint32_t u; } v; v.f = f;
  uint32_t u = v.u;
  return (uint16_t)((u + 0x7FFFu + ((u >> 16) & 1u)) >> 16);
}

__device__ __forceinline__ float tanh_fast(float x) {
  float e = __expf(2.0f * x);
  return 1.0f - 2.0f * __builtin_amdgcn_rcpf(e + 1.0f);
}

// ---------------- Kernel A: prep (unchanged) ----------------
__global__ __launch_bounds__(256) void prep_kernel(
    const float* __restrict__ dec,   // (32,512)
    const float* __restrict__ Watt,  // (1536,512)
    const float* __restrict__ batt,  // (512)
    float* __restrict__ cbias,       // ws (32*512)
    uint16_t* __restrict__ Wb,       // ws (1024*512 bf16, image layout)
    float* __restrict__ out)         // d_out (32768) -> zero
{
  const int t = blockIdx.x * 256 + threadIdx.x;  // [0,16384)

  for (int i = t; i < 32768; i += 16384) out[i] = 0.0f;

  // cbias: one output per thread. b = t>>9, d = t&511.
  {
    const int b = t >> 9, d = t & 511;
    const float* wd = Watt + 1024 * 512 + d;
    const float* dv = dec + b * 512;
    float s0 = 0.f, s1 = 0.f, s2 = 0.f, s3 = 0.f;
    #pragma unroll 4
    for (int k = 0; k < 512; k += 4) {
      s0 += dv[k + 0] * wd[(k + 0) * 512];
      s1 += dv[k + 1] * wd[(k + 1) * 512];
      s2 += dv[k + 2] * wd[(k + 2) * 512];
      s3 += dv[k + 3] * wd[(k + 3) * 512];
    }
    cbias[t] = batt[d] + ((s0 + s1) + (s2 + s3));
  }

  // W image (BK=32): chunk c, row d, 16B unit t in [0,4):
  //   unit (c*2048 + d*4 + t) holds W_enc[c*32 + (t ^ ((d>>1)&3))*8 + i][d]
  // so a LINEAR gload_lds copy yields LDS where a read at byte
  //   d*64 + ((l4*16) ^ (((d>>1)&3)<<4))  returns k-group l4 (bank-spread).
  uint4* WbV = (uint4*)Wb;
  #pragma unroll
  for (int i = 0; i < 4; ++i) {
    const int u = t + 16384 * i;      // [0,65536)
    const int c  = u >> 11;           // chunk
    const int w  = u & 2047;
    const int d  = w >> 2;
    const int tt = w & 3;
    const int kb = c * 32 + ((tt ^ ((d >> 1) & 3)) << 3);
    uint32_t h[8];
    #pragma unroll
    for (int kk = 0; kk < 8; ++kk) {
      float f = Watt[(size_t)(kb + kk) * 512 + d];
      h[kk] = f32_to_bf16_rne(f);
    }
    uint4 val;
    val.x = h[0] | (h[1] << 16);
    val.y = h[2] | (h[3] << 16);
    val.z = h[4] | (h[5] << 16);
    val.w = h[6] | (h[7] << 16);
    WbV[u] = val;
  }
}

// ---------------- Kernel B: fused energy GEMM + tanh + dot(v), v6 ----------------
// v6 = v5 geometry halved: 1024 blocks x 512 threads (8 waves, 1x8).
// BM=64, BN=512, BK=32. LDS: A dbuf 2x4KB + B dbuf 2x32KB = 72 KB.
// => TWO independent 8-wave blocks per CU (72KB*2 <= 160KB; ~124 unified regs
// @ 4 waves/SIMD). Independent barrier domains overlap each other's
// per-chunk bubbles (m114 mechanism) — the single-16-wave-block v5 could not.
// Schedule per chunk (1 barrier, counted vmcnt): write A(c); issue av(c+1);
// vmcnt(1) [drain B(c)'s 4 gload_lds, keep av(c+1)]; lgkmcnt(0); s_barrier;
// issue B(c+1); compute(c).
__global__ __launch_bounds__(512, 4) void energy_kernel(
    const float* __restrict__ x,       // (65536,1024)
    const uint16_t* __restrict__ Wb,   // W image (1 MiB)
    const float* __restrict__ cbias,   // (32,512)
    const float* __restrict__ vvec,    // (512)
    float* __restrict__ att)           // (65536), fully overwritten
{
  __shared__ __align__(16) uint8_t AL[2][64 * 64];     // 2 x 4 KB
  __shared__ __align__(16) uint8_t BL[2][512 * 64];    // 2 x 32 KB

  const int tid  = threadIdx.x;
  const int lane = tid & 63;
  const int wave = tid >> 6;           // 0..7 = wn (64-col group)
  const int l15  = lane & 15;
  const int l4   = lane >> 4;
  const int brow0 = blockIdx.x * 64;
  const int b     = brow0 >> 11;

  // A staging: 1 float4/thread: r = tid>>3 in [0,64), q = tid&7
  const int r_st = tid >> 3, q_st = tid & 7;
  const int aoff = r_st * 64 + ((q_st * 8) ^ (((r_st >> 1) & 3) << 4));
  const float* asrc = x + (size_t)(brow0 + r_st) * 1024 + q_st * 4;
  const uint8_t* wbase = (const uint8_t*)Wb + (lane << 4);

  f32x4 acc[4][4];
  #pragma unroll
  for (int mf = 0; mf < 4; ++mf)
    #pragma unroll
    for (int nf = 0; nf < 4; ++nf)
      acc[mf][nf] = (f32x4){0.f, 0.f, 0.f, 0.f};

  // prologue: av(0) first (oldest in vmcnt FIFO), then B(0)'s 4 gload_lds
  float4 av = *(const float4*)(asrc);
  #pragma unroll
  for (int i = 0; i < 4; ++i) {
    const int u = i * 8 + wave;        // [0,32) 1KB units
    __builtin_amdgcn_global_load_lds(
        (const __attribute__((address_space(1))) uint32_t*)(wbase + u * 1024),
        (__attribute__((address_space(3))) uint32_t*)(&BL[0][u * 1024]),
        16, 0, 0);
  }

  #pragma unroll 2
  for (int c = 0; c < 32; ++c) {
    uint8_t* Ab = AL[c & 1];
    uint8_t* Bb = BL[c & 1];

    // write A(c) (compiler emits counted vmcnt for av only; B(c) stays)
    {
      uint32_t lo = (uint32_t)f32_to_bf16_rne(av.x) | ((uint32_t)f32_to_bf16_rne(av.y) << 16);
      uint32_t hi = (uint32_t)f32_to_bf16_rne(av.z) | ((uint32_t)f32_to_bf16_rne(av.w) << 16);
      *(uint2*)(Ab + aoff) = make_uint2(lo, hi);
    }

    if (c < 31) {
      av = *(const float4*)(asrc + (c + 1) * 32);       // issue av(c+1)
      asm volatile("s_waitcnt vmcnt(1)" ::: "memory");  // drain B(c)'s 4 only
    } else {
      asm volatile("s_waitcnt vmcnt(0)" ::: "memory");
    }
    asm volatile("s_waitcnt lgkmcnt(0)" ::: "memory");
    __builtin_amdgcn_s_barrier();
    asm volatile("" ::: "memory");

    if (c < 31) {  // issue B(c+1) post-barrier; lands during compute(c)
      const uint8_t* wc = wbase + ((size_t)(c + 1) << 15);
      uint8_t* Bn = BL[(c + 1) & 1];
      #pragma unroll
      for (int i = 0; i < 4; ++i) {
        const int u = i * 8 + wave;
        __builtin_amdgcn_global_load_lds(
            (const __attribute__((address_space(1))) uint32_t*)(wc + u * 1024),
            (__attribute__((address_space(3))) uint32_t*)(Bn + u * 1024),
            16, 0, 0);
      }
    }

    // compute chunk c: 8 ds_read_b128 + 16 MFMA per wave
    bf16x8 af[4], bfr[4];
    #pragma unroll
    for (int mf = 0; mf < 4; ++mf) {
      const int r = mf * 16 + l15;
      af[mf] = *(const bf16x8*)(Ab + r * 64 + ((l4 * 16) ^ (((r >> 1) & 3) << 4)));
    }
    #pragma unroll
    for (int nf = 0; nf < 4; ++nf) {
      const int d = wave * 64 + nf * 16 + l15;
      bfr[nf] = *(const bf16x8*)(Bb + d * 64 + ((l4 * 16) ^ (((d >> 1) & 3) << 4)));
    }
    #pragma unroll
    for (int mf = 0; mf < 4; ++mf)
      #pragma unroll
      for (int nf = 0; nf < 4; ++nf)
        acc[mf][nf] = __builtin_amdgcn_mfma_f32_16x16x32_bf16(af[mf], bfr[nf], acc[mf][nf], 0, 0, 0);
  }

  // ---- epilogue: tanh + dot(v); LDS-atomic reduce across the 8 waves ----
  float cb[4], vv[4];
  #pragma unroll
  for (int nf = 0; nf < 4; ++nf) {
    const int d = wave * 64 + nf * 16 + l15;
    cb[nf] = cbias[b * 512 + d];
    vv[nf] = vvec[d];
  }

  __syncthreads();                       // all waves done reading AL
  float* red = (float*)AL;               // reuse 256 B of A space
  if (tid < 64) red[tid] = 0.0f;
  __syncthreads();

  #pragma unroll
  for (int mf = 0; mf < 4; ++mf) {
    float s[4] = {0.f, 0.f, 0.f, 0.f};
    #pragma unroll
    for (int nf = 0; nf < 4; ++nf) {
      #pragma unroll
      for (int j = 0; j < 4; ++j) {
        const float e = acc[mf][nf][j] + cb[nf];
        s[j] += tanh_fast(e) * vv[nf];
      }
    }
    #pragma unroll
    for (int j = 0; j < 4; ++j) {
      float r = s[j];
      r += __shfl_xor(r, 1);
      r += __shfl_xor(r, 2);
      r += __shfl_xor(r, 4);
      r += __shfl_xor(r, 8);
      if (l15 == 0) atomicAdd(&red[mf * 16 + 4 * l4 + j], r);
    }
  }
  __syncthreads();
  if (tid < 64) att[brow0 + tid] = red[tid];
}

// ---------------- Kernel C: softmax over S (in place) ----------------
__global__ __launch_bounds__(256) void softmax_kernel(float* __restrict__ att) {
  const int b = blockIdx.x;
  float* row = att + b * 2048;
  const int tid = threadIdx.x;
  __shared__ float redm[4], reds[4];

  float vals[8];
  float m = -1e30f;
  #pragma unroll
  for (int i = 0; i < 8; ++i) { vals[i] = row[tid + 256 * i]; m = fmaxf(m, vals[i]); }
  #pragma unroll
  for (int msk = 1; msk < 64; msk <<= 1) m = fmaxf(m, __shfl_xor(m, msk));
  if ((tid & 63) == 0) redm[tid >> 6] = m;
  __syncthreads();
  m = fmaxf(fmaxf(redm[0], redm[1]), fmaxf(redm[2], redm[3]));

  float s = 0.f;
  #pragma unroll
  for (int i = 0; i < 8; ++i) { vals[i] = __expf(vals[i] - m); s += vals[i]; }
  #pragma unroll
  for (int msk = 1; msk < 64; msk <<= 1) s += __shfl_xor(s, msk);
  if ((tid & 63) == 0) reds[tid >> 6] = s;
  __syncthreads();
  const float inv = 1.0f / (((reds[0] + reds[1]) + (reds[2] + reds[3])));
  #pragma unroll
  for (int i = 0; i < 8; ++i) row[tid + 256 * i] = vals[i] * inv;
}

// ---------------- Kernel D: context = w @ x ----------------
__global__ __launch_bounds__(256) void context_kernel(
    const float* __restrict__ x,   // (65536,1024)
    const float* __restrict__ w,   // (32,2048)
    float* __restrict__ out)       // (32,1024), pre-zeroed
{
  const int blk = blockIdx.x;
  const int b = blk >> 4, sc = blk & 15;
  const int tid = threadIdx.x;
  const float* xb = x + ((size_t)(b * 2048 + sc * 128)) * 1024 + tid * 4;
  const float* wb = w + b * 2048 + sc * 128;

  float4 acc = {0.f, 0.f, 0.f, 0.f};
  for (int si = 0; si < 128; ++si) {
    const float ww = wb[si];
    const float4 xv = *(const float4*)(xb + (size_t)si * 1024);
    acc.x += ww * xv.x;
    acc.y += ww * xv.y;
    acc.z += ww * xv.z;
    acc.w += ww * xv.w;
  }
  float* o = out + b * 1024 + tid * 4;
  atomicAdd(o + 0, acc.x);
  atomicAdd(o + 1, acc.y);
  atomicAdd(o + 2, acc.z);
  atomicAdd(o + 3, acc.w);
}

extern "C" void kernel_launch(void* const* d_in, const int* in_sizes, int n_in,
                              void* d_out, int out_size, void* d_ws, size_t ws_size,
                              hipStream_t stream) {
  const float* x    = (const float*)d_in[0];  // (32,2048,1024)
  const float* dec  = (const float*)d_in[1];  // (32,512)
  const float* Watt = (const float*)d_in[2];  // (1536,512)
  const float* batt = (const float*)d_in[3];  // (512)
  const float* v    = (const float*)d_in[4];  // (512)
  float* out = (float*)d_out;

  uint8_t* ws = (uint8_t*)d_ws;
  float*    att   = (float*)ws;                        // 256 KB
  float*    cbias = (float*)(ws + 256 * 1024);         // 64 KB
  uint16_t* Wb    = (uint16_t*)(ws + 320 * 1024);      // 1 MiB

  prep_kernel<<<64, 256, 0, stream>>>(dec, Watt, batt, cbias, Wb, out);
  energy_kernel<<<1024, 512, 0, stream>>>(x, Wb, cbias, v, att);
  softmax_kernel<<<32, 256, 0, stream>>>(att);
  context_kernel<<<512, 256, 0, stream>>>(x, att, out);
}

// Round 7
// 143.766 us; speedup vs baseline: 7.6878x; 1.0865x over previous
//
#include <hip/hip_runtime.h>
#include <stdint.h>

// Problem: B=32, S=2048, E2=1024, D=512
//   c[b][d]    = b_att[d] + sum_k dec[b][k] * W_att[1024+k][d]
//   att[b][s]  = sum_d tanh( sum_e x[b][s][e]*W_att[e][d] + c[b][d] ) * v[d]
//   w          = softmax(att, axis=s)
//   out[b][e]  = sum_s w[b][s] * x[b][s][e]
//
// ws layout: [0,256K) attention f32[65536]; [256K,320K) cbias f32[16384];
//            [320K,320K+1MiB) W_enc bf16 "fragment image":
//   16B unit index  u = c*2048 + wn*256 + nf*64 + lane   (c=K-chunk of 32)
//   holds W_enc[c*32 + (lane>>4)*8 + j][wn*64 + nf*16 + (lane&15)], j=0..7
// => wave wn's B-fragment for (c,nf) is ONE coalesced 1KB global load
//    (global_load_dwordx4 per lane), exactly in MFMA B-operand layout.

typedef __attribute__((ext_vector_type(8))) __bf16 bf16x8;
typedef __attribute__((ext_vector_type(4))) float f32x4;

__device__ __forceinline__ uint16_t f32_to_bf16_rne(float f) {
  union { float f; uint32_t u; } v; v.f = f;
  uint32_t u = v.u;
  return (uint16_t)((u + 0x7FFFu + ((u >> 16) & 1u)) >> 16);
}

__device__ __forceinline__ float tanh_fast(float x) {
  float e = __expf(2.0f * x);
  return 1.0f - 2.0f * __builtin_amdgcn_rcpf(e + 1.0f);
}

// ---------------- Kernel A: prep ----------------
__global__ __launch_bounds__(256) void prep_kernel(
    const float* __restrict__ dec,   // (32,512)
    const float* __restrict__ Watt,  // (1536,512)
    const float* __restrict__ batt,  // (512)
    float* __restrict__ cbias,       // ws (32*512)
    uint16_t* __restrict__ Wb,       // ws (1 MiB fragment image)
    float* __restrict__ out)         // d_out (32768) -> zero
{
  const int t = blockIdx.x * 256 + threadIdx.x;  // [0,16384)

  for (int i = t; i < 32768; i += 16384) out[i] = 0.0f;

  // cbias: one output per thread. b = t>>9, d = t&511.
  {
    const int b = t >> 9, d = t & 511;
    const float* wd = Watt + 1024 * 512 + d;
    const float* dv = dec + b * 512;
    float s0 = 0.f, s1 = 0.f, s2 = 0.f, s3 = 0.f;
    #pragma unroll 4
    for (int k = 0; k < 512; k += 4) {
      s0 += dv[k + 0] * wd[(k + 0) * 512];
      s1 += dv[k + 1] * wd[(k + 1) * 512];
      s2 += dv[k + 2] * wd[(k + 2) * 512];
      s3 += dv[k + 3] * wd[(k + 3) * 512];
    }
    cbias[t] = batt[d] + ((s0 + s1) + (s2 + s3));
  }

  // W fragment image: 65536 16-byte units, 4 per thread.
  uint4* WbV = (uint4*)Wb;
  #pragma unroll
  for (int i = 0; i < 4; ++i) {
    const int u   = t + 16384 * i;    // [0,65536)
    const int c   = u >> 11;          // K-chunk
    const int rem = u & 2047;
    const int wn  = rem >> 8;         // 0..7
    const int nf  = (rem >> 6) & 3;   // 0..3
    const int ln  = rem & 63;         // lane
    const int kb  = c * 32 + ((ln >> 4) << 3);
    const int d   = wn * 64 + nf * 16 + (ln & 15);
    uint32_t h[8];
    #pragma unroll
    for (int kk = 0; kk < 8; ++kk) {
      float f = Watt[(size_t)(kb + kk) * 512 + d];
      h[kk] = f32_to_bf16_rne(f);
    }
    uint4 val;
    val.x = h[0] | (h[1] << 16);
    val.y = h[2] | (h[3] << 16);
    val.z = h[4] | (h[5] << 16);
    val.w = h[6] | (h[7] << 16);
    WbV[u] = val;
  }
}

// ---------------- Kernel B: fused energy GEMM + tanh + dot(v), v7 ----------------
// v7: B NEVER touches LDS. Per chunk, each wave loads its 4 private B-fragments
// (4 KB, contiguous, L2-hit) straight into registers, double-buffered one chunk
// ahead (bA/bB named sets). LDS holds only the A tile (64x32 bf16, dbuf 8 KB).
// The barrier coordinates A staging only; all global-load waiting is
// compiler-managed counted vmcnt (no gload_lds, no manual FIFO discipline).
// 1024 blocks x 512 threads (8 waves); 2 blocks/CU (regs <=128, LDS 8 KB).
__global__ __launch_bounds__(512, 4) void energy_kernel(
    const float* __restrict__ x,       // (65536,1024)
    const uint16_t* __restrict__ Wb,   // fragment image (1 MiB)
    const float* __restrict__ cbias,   // (32,512)
    const float* __restrict__ vvec,    // (512)
    float* __restrict__ att)           // (65536), fully overwritten
{
  __shared__ __align__(16) uint8_t AL[2][64 * 64];     // 2 x 4 KB : A 64r x 32k bf16

  const int tid  = threadIdx.x;
  const int lane = tid & 63;
  const int wave = tid >> 6;           // 0..7 = wn (64-col group)
  const int l15  = lane & 15;
  const int l4   = lane >> 4;
  const int brow0 = blockIdx.x * 64;
  const int b     = brow0 >> 11;

  // A staging: 1 float4/thread: r = tid>>3 in [0,64), q = tid&7
  const int r_st = tid >> 3, q_st = tid & 7;
  const int aoff = r_st * 64 + ((q_st * 8) ^ (((r_st >> 1) & 3) << 4));
  const float* asrc = x + (size_t)(brow0 + r_st) * 1024 + q_st * 4;
  // this wave's B slice: 4 fragments x 1 KB per chunk, chunk stride 32 KB
  const uint8_t* wslice = (const uint8_t*)Wb + (size_t)wave * 4096 + (size_t)lane * 16;

  f32x4 acc[4][4];
  #pragma unroll
  for (int mf = 0; mf < 4; ++mf)
    #pragma unroll
    for (int nf = 0; nf < 4; ++nf)
      acc[mf][nf] = (f32x4){0.f, 0.f, 0.f, 0.f};

  // prologue: av(0) + B(0) fragments
  float4 av_cur = *(const float4*)(asrc);
  bf16x8 bA[4], bB[4];
  {
    const bf16x8* bs = (const bf16x8*)(wslice);
    bA[0] = bs[0]; bA[1] = bs[64]; bA[2] = bs[128]; bA[3] = bs[192];
  }

// Per chunk c: ds_write A(c) [compiler waits av(c) only]; issue av(c+1);
// lgkmcnt(0); s_barrier  [no vmcnt drain -- B/av prefetches stay in flight];
// issue B(c+1) into BNXT; 4x { ds_read af; 4 MFMA with BCUR }.
// dbuf safety: passing barrier(c) implies all waves finished compute(c-1)
// (and hence compute(c-2), which read AL[c&1]) -- write/read race-free.
#define CHUNK(C, BCUR, BNXT)                                                   \
  {                                                                            \
    const int c_ = (C);                                                        \
    uint8_t* Ab = AL[c_ & 1];                                                  \
    uint32_t lo_ = (uint32_t)f32_to_bf16_rne(av_cur.x) |                       \
                   ((uint32_t)f32_to_bf16_rne(av_cur.y) << 16);                \
    uint32_t hi_ = (uint32_t)f32_to_bf16_rne(av_cur.z) |                       \
                   ((uint32_t)f32_to_bf16_rne(av_cur.w) << 16);                \
    *(uint2*)(Ab + aoff) = make_uint2(lo_, hi_);                               \
    const int cn_ = (c_ < 31) ? c_ + 1 : 31;                                   \
    av_cur = *(const float4*)(asrc + cn_ * 32);                                \
    asm volatile("s_waitcnt lgkmcnt(0)" ::: "memory");                         \
    __builtin_amdgcn_s_barrier();                                              \
    asm volatile("" ::: "memory");                                             \
    {                                                                          \
      const bf16x8* bs_ = (const bf16x8*)(wslice + (size_t)cn_ * 32768);       \
      BNXT[0] = bs_[0]; BNXT[1] = bs_[64];                                     \
      BNXT[2] = bs_[128]; BNXT[3] = bs_[192];                                  \
    }                                                                          \
    _Pragma("unroll")                                                          \
    for (int mf = 0; mf < 4; ++mf) {                                           \
      const int r_ = mf * 16 + l15;                                            \
      bf16x8 afm = *(const bf16x8*)(Ab + r_ * 64 +                             \
                                    ((l4 * 16) ^ (((r_ >> 1) & 3) << 4)));     \
      acc[mf][0] = __builtin_amdgcn_mfma_f32_16x16x32_bf16(afm, BCUR[0], acc[mf][0], 0, 0, 0); \
      acc[mf][1] = __builtin_amdgcn_mfma_f32_16x16x32_bf16(afm, BCUR[1], acc[mf][1], 0, 0, 0); \
      acc[mf][2] = __builtin_amdgcn_mfma_f32_16x16x32_bf16(afm, BCUR[2], acc[mf][2], 0, 0, 0); \
      acc[mf][3] = __builtin_amdgcn_mfma_f32_16x16x32_bf16(afm, BCUR[3], acc[mf][3], 0, 0, 0); \
    }                                                                          \
  }

  for (int c = 0; c < 32; c += 2) {
    CHUNK(c, bA, bB);
    CHUNK(c + 1, bB, bA);
  }
#undef CHUNK

  // ---- epilogue: tanh + dot(v); LDS-atomic reduce across the 8 waves ----
  float cb[4], vv[4];
  #pragma unroll
  for (int nf = 0; nf < 4; ++nf) {
    const int d = wave * 64 + nf * 16 + l15;
    cb[nf] = cbias[b * 512 + d];
    vv[nf] = vvec[d];
  }

  __syncthreads();                       // all waves done reading AL
  float* red = (float*)AL;               // reuse 256 B of A space
  if (tid < 64) red[tid] = 0.0f;
  __syncthreads();

  #pragma unroll
  for (int mf = 0; mf < 4; ++mf) {
    float s[4] = {0.f, 0.f, 0.f, 0.f};
    #pragma unroll
    for (int nf = 0; nf < 4; ++nf) {
      #pragma unroll
      for (int j = 0; j < 4; ++j) {
        const float e = acc[mf][nf][j] + cb[nf];
        s[j] += tanh_fast(e) * vv[nf];
      }
    }
    #pragma unroll
    for (int j = 0; j < 4; ++j) {
      float r = s[j];
      r += __shfl_xor(r, 1);
      r += __shfl_xor(r, 2);
      r += __shfl_xor(r, 4);
      r += __shfl_xor(r, 8);
      if (l15 == 0) atomicAdd(&red[mf * 16 + 4 * l4 + j], r);
    }
  }
  __syncthreads();
  if (tid < 64) att[brow0 + tid] = red[tid];
}

// ---------------- Kernel C: softmax over S (in place) ----------------
__global__ __launch_bounds__(256) void softmax_kernel(float* __restrict__ att) {
  const int b = blockIdx.x;
  float* row = att + b * 2048;
  const int tid = threadIdx.x;
  __shared__ float redm[4], reds[4];

  float vals[8];
  float m = -1e30f;
  #pragma unroll
  for (int i = 0; i < 8; ++i) { vals[i] = row[tid + 256 * i]; m = fmaxf(m, vals[i]); }
  #pragma unroll
  for (int msk = 1; msk < 64; msk <<= 1) m = fmaxf(m, __shfl_xor(m, msk));
  if ((tid & 63) == 0) redm[tid >> 6] = m;
  __syncthreads();
  m = fmaxf(fmaxf(redm[0], redm[1]), fmaxf(redm[2], redm[3]));

  float s = 0.f;
  #pragma unroll
  for (int i = 0; i < 8; ++i) { vals[i] = __expf(vals[i] - m); s += vals[i]; }
  #pragma unroll
  for (int msk = 1; msk < 64; msk <<= 1) s += __shfl_xor(s, msk);
  if ((tid & 63) == 0) reds[tid >> 6] = s;
  __syncthreads();
  const float inv = 1.0f / (((reds[0] + reds[1]) + (reds[2] + reds[3])));
  #pragma unroll
  for (int i = 0; i < 8; ++i) row[tid + 256 * i] = vals[i] * inv;
}

// ---------------- Kernel D: context = w @ x ----------------
__global__ __launch_bounds__(256) void context_kernel(
    const float* __restrict__ x,   // (65536,1024)
    const float* __restrict__ w,   // (32,2048)
    float* __restrict__ out)       // (32,1024), pre-zeroed
{
  const int blk = blockIdx.x;
  const int b = blk >> 4, sc = blk & 15;
  const int tid = threadIdx.x;
  const float* xb = x + ((size_t)(b * 2048 + sc * 128)) * 1024 + tid * 4;
  const float* wb = w + b * 2048 + sc * 128;

  float4 acc = {0.f, 0.f, 0.f, 0.f};
  for (int si = 0; si < 128; ++si) {
    const float ww = wb[si];
    const float4 xv = *(const float4*)(xb + (size_t)si * 1024);
    acc.x += ww * xv.x;
    acc.y += ww * xv.y;
    acc.z += ww * xv.z;
    acc.w += ww * xv.w;
  }
  float* o = out + b * 1024 + tid * 4;
  atomicAdd(o + 0, acc.x);
  atomicAdd(o + 1, acc.y);
  atomicAdd(o + 2, acc.z);
  atomicAdd(o + 3, acc.w);
}

extern "C" void kernel_launch(void* const* d_in, const int* in_sizes, int n_in,
                              void* d_out, int out_size, void* d_ws, size_t ws_size,
                              hipStream_t stream) {
  const float* x    = (const float*)d_in[0];  // (32,2048,1024)
  const float* dec  = (const float*)d_in[1];  // (32,512)
  const float* Watt = (const float*)d_in[2];  // (1536,512)
  const float* batt = (const float*)d_in[3];  // (512)
  const float* v    = (const float*)d_in[4];  // (512)
  float* out = (float*)d_out;

  uint8_t* ws = (uint8_t*)d_ws;
  float*    att   = (float*)ws;                        // 256 KB
  float*    cbias = (float*)(ws + 256 * 1024);         // 64 KB
  uint16_t* Wb    = (uint16_t*)(ws + 320 * 1024);      // 1 MiB

  prep_kernel<<<64, 256, 0, stream>>>(dec, Watt, batt, cbias, Wb, out);
  energy_kernel<<<1024, 512, 0, stream>>>(x, Wb, cbias, v, att);
  softmax_kernel<<<32, 256, 0, stream>>>(att);
  context_kernel<<<512, 256, 0, stream>>>(x, att, out);
}